// Round 1
// baseline (836.044 us; speedup 1.0000x reference)
//
#include <hip/hip_runtime.h>
#include <hip/hip_bf16.h>

// Problem constants (fixed by the reference)
#define B_    4
#define L_    2048
#define INK   256     // input feature dim for K/Q/V
#define HID   1024
#define NH    8       // heads
#define DH    128     // head dim
#define OUTF  256

typedef __bf16 v8bf __attribute__((ext_vector_type(8)));
typedef float  v4f  __attribute__((ext_vector_type(4)));

#define MFMA(a,b,c) __builtin_amdgcn_mfma_f32_16x16x32_bf16((a),(b),(c),0,0,0)

// Load 8 consecutive fp32, convert to bf16 fragment (RNE via cast)
__device__ inline v8bf ld8_f32(const float* __restrict__ p) {
  const float4 x = *(const float4*)p;
  const float4 y = *(const float4*)(p + 4);
  v8bf v;
  v[0] = (__bf16)x.x; v[1] = (__bf16)x.y; v[2] = (__bf16)x.z; v[3] = (__bf16)x.w;
  v[4] = (__bf16)y.x; v[5] = (__bf16)y.y; v[6] = (__bf16)y.z; v[7] = (__bf16)y.w;
  return v;
}
__device__ inline v8bf ld8_bf(const __bf16* __restrict__ p) {
  return *(const v8bf*)p;
}
__device__ inline unsigned short bfbits(float f) {
  __bf16 h = (__bf16)f;
  return __builtin_bit_cast(unsigned short, h);
}

// ---------------------------------------------------------------------------
// Kernel 1: projection  P[m][n] = sum_c X[m][c]*W[n][c] + bias[n], cast bf16
// MODE 0 (K/Q): out[((b*8+h)*L + i)*128 + dd]   (h = n&7, dd = n>>3, m = b*L+i)
// MODE 1 (V):   out[((b*8+h)*128 + dd)*L + i]   (transposed for PV A-operand)
// Workgroup: 256 thr = 4 waves (2x2), each wave a 64x64 tile; wg tile 128x128.
// Grid: (M/128, N/128) = (64, 8)
// ---------------------------------------------------------------------------
template<int MODE>
__global__ __launch_bounds__(256)
void proj_kernel(const float* __restrict__ X, const float* __restrict__ W,
                 const float* __restrict__ bias, __bf16* __restrict__ out)
{
  const int lane = threadIdx.x & 63;
  const int wid  = threadIdx.x >> 6;
  const int l15  = lane & 15;
  const int q    = lane >> 4;
  const int m_base = blockIdx.x * 128 + (wid & 1) * 64;
  const int n_base = blockIdx.y * 128 + (wid >> 1) * 64;

  v4f acc[4][4];
  const v4f vz = {0.f, 0.f, 0.f, 0.f};
#pragma unroll
  for (int a = 0; a < 4; a++)
#pragma unroll
    for (int b = 0; b < 4; b++) acc[a][b] = vz;

#pragma unroll
  for (int k0 = 0; k0 < INK; k0 += 32) {
    v8bf af[4], bf[4];
#pragma unroll
    for (int t = 0; t < 4; t++)
      af[t] = ld8_f32(X + (size_t)(m_base + t * 16 + l15) * INK + k0 + q * 8);
#pragma unroll
    for (int t = 0; t < 4; t++)
      bf[t] = ld8_f32(W + (size_t)(n_base + t * 16 + l15) * INK + k0 + q * 8);
#pragma unroll
    for (int tm = 0; tm < 4; tm++)
#pragma unroll
      for (int tn = 0; tn < 4; tn++)
        acc[tm][tn] = MFMA(af[tm], bf[tn], acc[tm][tn]);
  }

#pragma unroll
  for (int tn = 0; tn < 4; tn++) {
    const int n  = n_base + tn * 16 + l15;
    const float bv = bias[n];
    const int h  = n & 7;
    const int dd = n >> 3;
#pragma unroll
    for (int tm = 0; tm < 4; tm++) {
#pragma unroll
      for (int r = 0; r < 4; r++) {
        const int m = m_base + tm * 16 + q * 4 + r;
        const int b = m >> 11;        // m / L_
        const int i = m & (L_ - 1);   // m % L_
        const float v = acc[tm][tn][r] + bv;
        size_t idx;
        if (MODE == 0) idx = ((size_t)(b * NH + h) * L_ + i) * DH + dd;
        else           idx = ((size_t)(b * NH + h) * DH + dd) * L_ + i;
        out[idx] = (__bf16)v;
      }
    }
  }
}

// ---------------------------------------------------------------------------
// Kernel 2 (pass B, per batch): all-head scores + softmax over heads.
// S[h][i][k] = sum_d Kp[h][i][d]*Qp[h][k][d];  P = exp(S/sqrt(D)) / sum_h(...)
// Writes NORMALIZED attn transposed: Pt[h][k][i] (bf16), i contiguous.
// Workgroup 256 thr = 4 waves; wave w: i-strip of 16 rows x 64 k, ALL 8 heads
// in registers (acc[8][4] = 128 VGPRs). Grid: (L/64, L/64) = (32, 32).
// ---------------------------------------------------------------------------
__global__ __launch_bounds__(256)
void score_softmax_kernel(const __bf16* __restrict__ Kp,
                          const __bf16* __restrict__ Qp,
                          __bf16* __restrict__ Pt)
{
  const int lane = threadIdx.x & 63;
  const int wid  = threadIdx.x >> 6;
  const int l15  = lane & 15;
  const int q    = lane >> 4;
  const int i0 = blockIdx.x * 64 + wid * 16;
  const int k0 = blockIdx.y * 64;

  v4f acc[8][4];
  const v4f vz = {0.f, 0.f, 0.f, 0.f};
#pragma unroll
  for (int h = 0; h < 8; h++)
#pragma unroll
    for (int t = 0; t < 4; t++) acc[h][t] = vz;

#pragma unroll
  for (int h = 0; h < 8; h++) {
    const __bf16* __restrict__ Kh = Kp + (size_t)h * L_ * DH;
    const __bf16* __restrict__ Qh = Qp + (size_t)h * L_ * DH;
#pragma unroll
    for (int d0 = 0; d0 < DH; d0 += 32) {
      const v8bf a = ld8_bf(Kh + (size_t)(i0 + l15) * DH + d0 + q * 8);
#pragma unroll
      for (int t = 0; t < 4; t++) {
        const v8bf b = ld8_bf(Qh + (size_t)(k0 + t * 16 + l15) * DH + d0 + q * 8);
        acc[h][t] = MFMA(a, b, acc[h][t]);
      }
    }
  }

  // softmax over heads: scores tiny (|s|<~1), no max-subtraction needed
  const float c2 = 0.12751744f;  // log2(e)/sqrt(128)
  v4f z[4];
#pragma unroll
  for (int t = 0; t < 4; t++) z[t] = vz;
#pragma unroll
  for (int h = 0; h < 8; h++)
#pragma unroll
    for (int t = 0; t < 4; t++)
#pragma unroll
      for (int r = 0; r < 4; r++) {
        const float p = exp2f(acc[h][t][r] * c2);
        acc[h][t][r] = p;
        z[t][r] += p;
      }
#pragma unroll
  for (int t = 0; t < 4; t++)
#pragma unroll
    for (int r = 0; r < 4; r++) z[t][r] = 1.0f / z[t][r];

  // write normalized attn to Pt[h][k][i], 4 consecutive i per lane => 8B store
#pragma unroll
  for (int h = 0; h < 8; h++) {
#pragma unroll
    for (int t = 0; t < 4; t++) {
      const int k = k0 + t * 16 + l15;
      const unsigned short b0 = bfbits(acc[h][t][0] * z[t][0]);
      const unsigned short b1 = bfbits(acc[h][t][1] * z[t][1]);
      const unsigned short b2 = bfbits(acc[h][t][2] * z[t][2]);
      const unsigned short b3 = bfbits(acc[h][t][3] * z[t][3]);
      uint2 w;
      w.x = (unsigned)b0 | ((unsigned)b1 << 16);
      w.y = (unsigned)b2 | ((unsigned)b3 << 16);
      *reinterpret_cast<uint2*>(Pt + (size_t)(h * L_ + k) * L_ + i0 + q * 4) = w;
    }
  }
}

// ---------------------------------------------------------------------------
// Kernel 3 (pass C, per batch): PV.  C[h][dd][k] = sum_i Vpt[h][dd][i]*P[i][k]
// A = Vpt[h] ([128][L], i contiguous), B^T = Pt[h] ([L][L], i contiguous).
// Store hidden[k][dd*8+h] bf16.  Workgroup 4 waves (2x2), wave tile 32x64,
// wg tile 64(dd) x 128(k). Grid: (L/128, 128/64, NH) = (16, 2, 8).
// ---------------------------------------------------------------------------
__global__ __launch_bounds__(256)
void pv_kernel(const __bf16* __restrict__ Vpt, const __bf16* __restrict__ Pt,
               __bf16* __restrict__ hidden)
{
  const int lane = threadIdx.x & 63;
  const int wid  = threadIdx.x >> 6;
  const int l15  = lane & 15;
  const int q    = lane >> 4;
  const int h = blockIdx.z;
  const int m_base = blockIdx.y * 64 + (wid & 1) * 32;    // dd
  const int n_base = blockIdx.x * 128 + (wid >> 1) * 64;  // k

  const __bf16* __restrict__ A  = Vpt + (size_t)h * DH * L_;
  const __bf16* __restrict__ Bt = Pt  + (size_t)h * L_ * L_;

  v4f acc[2][4];
  const v4f vz = {0.f, 0.f, 0.f, 0.f};
#pragma unroll
  for (int a = 0; a < 2; a++)
#pragma unroll
    for (int b = 0; b < 4; b++) acc[a][b] = vz;

  for (int i0 = 0; i0 < L_; i0 += 32) {
    v8bf af[2], bf[4];
#pragma unroll
    for (int t = 0; t < 2; t++)
      af[t] = ld8_bf(A + (size_t)(m_base + t * 16 + l15) * L_ + i0 + q * 8);
#pragma unroll
    for (int t = 0; t < 4; t++)
      bf[t] = ld8_bf(Bt + (size_t)(n_base + t * 16 + l15) * L_ + i0 + q * 8);
#pragma unroll
    for (int tm = 0; tm < 2; tm++)
#pragma unroll
      for (int tn = 0; tn < 4; tn++)
        acc[tm][tn] = MFMA(af[tm], bf[tn], acc[tm][tn]);
  }

#pragma unroll
  for (int tm = 0; tm < 2; tm++)
#pragma unroll
    for (int tn = 0; tn < 4; tn++)
#pragma unroll
      for (int r = 0; r < 4; r++) {
        const int dd = m_base + tm * 16 + q * 4 + r;
        const int k  = n_base + tn * 16 + l15;
        hidden[(size_t)k * HID + dd * NH + h] = (__bf16)acc[tm][tn][r];
      }
}

// ---------------------------------------------------------------------------
// Kernel 4: output projection. OUT[row][o] = sum_m Hd[row][m]*Wo[o][m] + bo[o]
// Workgroup 4 waves (2x2), wave tile 32x32, wg 64x64. Grid (8192/64, 256/64).
// ---------------------------------------------------------------------------
__global__ __launch_bounds__(256)
void outproj_kernel(const __bf16* __restrict__ Hd, const float* __restrict__ Wo,
                    const float* __restrict__ bo, float* __restrict__ out)
{
  const int lane = threadIdx.x & 63;
  const int wid  = threadIdx.x >> 6;
  const int l15  = lane & 15;
  const int q    = lane >> 4;
  const int m_base = blockIdx.x * 64 + (wid & 1) * 32;   // row (b*L + l)
  const int n_base = blockIdx.y * 64 + (wid >> 1) * 32;  // o

  v4f acc[2][2];
  const v4f vz = {0.f, 0.f, 0.f, 0.f};
#pragma unroll
  for (int a = 0; a < 2; a++)
#pragma unroll
    for (int b = 0; b < 2; b++) acc[a][b] = vz;

  for (int k0 = 0; k0 < HID; k0 += 32) {
    v8bf af[2], bf[2];
#pragma unroll
    for (int t = 0; t < 2; t++)
      af[t] = ld8_bf(Hd + (size_t)(m_base + t * 16 + l15) * HID + k0 + q * 8);
#pragma unroll
    for (int t = 0; t < 2; t++)
      bf[t] = ld8_f32(Wo + (size_t)(n_base + t * 16 + l15) * HID + k0 + q * 8);
#pragma unroll
    for (int tm = 0; tm < 2; tm++)
#pragma unroll
      for (int tn = 0; tn < 2; tn++)
        acc[tm][tn] = MFMA(af[tm], bf[tn], acc[tm][tn]);
  }

#pragma unroll
  for (int tn = 0; tn < 2; tn++) {
    const int n = n_base + tn * 16 + l15;
    const float bv = bo[n];
#pragma unroll
    for (int tm = 0; tm < 2; tm++)
#pragma unroll
      for (int r = 0; r < 4; r++) {
        const int row = m_base + tm * 16 + q * 4 + r;
        out[(size_t)row * OUTF + n] = acc[tm][tn][r] + bv;
      }
  }
}

// ---------------------------------------------------------------------------
// Launch. Workspace layout (bf16 elements):
//   Kp  [B][NH][L][DH]   8,388,608
//   Qp  [B][NH][L][DH]   8,388,608
//   Vpt [B][NH][DH][L]   8,388,608
//   Hd  [B][L][HID]      8,388,608
//   Pt  [NH][L][L]      33,554,432  (per-batch, reused b=0..3)
// Total 67,108,864 elems = 128 MiB.
// ---------------------------------------------------------------------------
extern "C" void kernel_launch(void* const* d_in, const int* in_sizes, int n_in,
                              void* d_out, int out_size, void* d_ws, size_t ws_size,
                              hipStream_t stream) {
  const float* KEY   = (const float*)d_in[0];
  const float* VALUE = (const float*)d_in[1];
  const float* QUERY = (const float*)d_in[2];
  const float* W_w   = (const float*)d_in[3];
  const float* W_b   = (const float*)d_in[4];
  const float* Wv_w  = (const float*)d_in[5];
  const float* Wv_b  = (const float*)d_in[6];
  const float* Wo_w  = (const float*)d_in[7];
  const float* Wo_b  = (const float*)d_in[8];
  float* out = (float*)d_out;

  __bf16* Kp  = (__bf16*)d_ws;
  __bf16* Qp  = Kp  + (size_t)8388608;
  __bf16* Vpt = Qp  + (size_t)8388608;
  __bf16* Hd  = Vpt + (size_t)8388608;
  __bf16* Pt  = Hd  + (size_t)8388608;

  const dim3 blk(256);
  proj_kernel<0><<<dim3(64, 8), blk, 0, stream>>>(KEY,   W_w,  W_b,  Kp);
  proj_kernel<0><<<dim3(64, 8), blk, 0, stream>>>(QUERY, W_w,  W_b,  Qp);
  proj_kernel<1><<<dim3(64, 8), blk, 0, stream>>>(VALUE, Wv_w, Wv_b, Vpt);

  const size_t perb = (size_t)NH * L_ * DH;  // 2,097,152 elements
  for (int b = 0; b < B_; b++) {
    score_softmax_kernel<<<dim3(32, 32), blk, 0, stream>>>(
        Kp + b * perb, Qp + b * perb, Pt);
    pv_kernel<<<dim3(16, 2, 8), blk, 0, stream>>>(
        Vpt + b * perb, Pt, Hd + b * perb);
  }
  outproj_kernel<<<dim3(128, 4), blk, 0, stream>>>(Hd, Wo_w, Wo_b, out);
}

// Round 2
// 444.196 us; speedup vs baseline: 1.8822x; 1.8822x over previous
//
#include <hip/hip_runtime.h>
#include <hip/hip_bf16.h>
#include <stdint.h>

// Problem constants
#define B_    4
#define L_    2048
#define INK   256
#define HID   1024
#define NH    8
#define DH    128
#define OUTF  256

typedef __bf16 v8bf __attribute__((ext_vector_type(8)));
typedef float  v4f  __attribute__((ext_vector_type(4)));

#define MFMA(a,b,c) __builtin_amdgcn_mfma_f32_16x16x32_bf16((a),(b),(c),0,0,0)

// async global->LDS, 16B per lane. ldsbase must be wave-uniform; HW writes
// ldsbase + lane*16. gsrc is per-lane.
__device__ __forceinline__ void gl_lds16(const void* gsrc, void* ldsbase) {
  __builtin_amdgcn_global_load_lds(
      (const __attribute__((address_space(1))) unsigned int*)(uintptr_t)gsrc,
      (__attribute__((address_space(3))) unsigned int*)(uint32_t)(uintptr_t)ldsbase,
      16, 0, 0);
}

__device__ __forceinline__ unsigned short bfbits(float f) {
  __bf16 h = (__bf16)f;
  return __builtin_bit_cast(unsigned short, h);
}
__device__ __forceinline__ v8bf cvt8(float4 x, float4 y) {
  v8bf v;
  v[0]=(__bf16)x.x; v[1]=(__bf16)x.y; v[2]=(__bf16)x.z; v[3]=(__bf16)x.w;
  v[4]=(__bf16)y.x; v[5]=(__bf16)y.y; v[6]=(__bf16)y.z; v[7]=(__bf16)y.w;
  return v;
}

// ---------------------------------------------------------------------------
// Convert fp32 arrays -> bf16 (KEY, QUERY, VALUE, W_w, Wv_w)
// ---------------------------------------------------------------------------
struct ConvArgs {
  const float* src[5];
  __bf16* dst[5];
  int n[5];
};
__global__ __launch_bounds__(256)
void convert_kernel(ConvArgs a) {
  const int r = blockIdx.y;
  const int i = (blockIdx.x * 256 + threadIdx.x) * 4;
  if (i >= a.n[r]) return;
  const float4 v = *(const float4*)(a.src[r] + i);
  const unsigned short b0 = bfbits(v.x), b1 = bfbits(v.y),
                       b2 = bfbits(v.z), b3 = bfbits(v.w);
  uint2 w;
  w.x = (unsigned)b0 | ((unsigned)b1 << 16);
  w.y = (unsigned)b2 | ((unsigned)b3 << 16);
  *reinterpret_cast<uint2*>(a.dst[r] + i) = w;
}

// ---------------------------------------------------------------------------
// Projection (bf16 NT GEMM, K=256): C[m][n] = sum_k X[m][k]*W[n][k] + bias[n]
// Block 256 thr / 4 waves (2x2 of 64x64), tile 128x128, chunk K=64, dbuf LDS.
// MODE 0: out[((b*8+h)*L+i)*128+dd]   MODE 1: out[((b*8+h)*128+dd)*L+i]
// Grid (64, 8).
// ---------------------------------------------------------------------------
template<int MODE>
__global__ __launch_bounds__(256, 2)
void proj_kernel(const __bf16* __restrict__ X, const __bf16* __restrict__ W,
                 const float* __restrict__ bias, __bf16* __restrict__ out)
{
  __shared__ __bf16 sA[2][128 * 64];
  __shared__ __bf16 sB[2][128 * 64];
  const int tid  = threadIdx.x;
  const int lane = tid & 63;
  const int wid  = tid >> 6;
  const int l15  = lane & 15;
  const int q    = lane >> 4;
  const int mblk = blockIdx.x * 128;
  const int nblk = blockIdx.y * 128;

  v4f acc[4][4];
  const v4f vz = {0.f, 0.f, 0.f, 0.f};
#pragma unroll
  for (int i = 0; i < 4; i++)
#pragma unroll
    for (int j = 0; j < 4; j++) acc[i][j] = vz;

  const char* Ab = (const char*)X + (size_t)mblk * 512;
  const char* Bb = (const char*)W + (size_t)nblk * 512;

  auto stage = [&](int p, int c) {
    const int koff = c * 128;  // bytes into row
#pragma unroll
    for (int j = 0; j < 4; j++) {
      const int slot = j * 256 + tid;
      const int row = slot >> 3, g = slot & 7;
      gl_lds16(Ab + (size_t)row * 512 + koff + ((g ^ (row & 7)) << 4),
               &sA[p][(j * 256 + wid * 64) * 8]);
    }
#pragma unroll
    for (int j = 0; j < 4; j++) {
      const int slot = j * 256 + tid;
      const int row = slot >> 3, g = slot & 7;
      gl_lds16(Bb + (size_t)row * 512 + koff + ((g ^ (row & 7)) << 4),
               &sB[p][(j * 256 + wid * 64) * 8]);
    }
  };

  stage(0, 0);
  __syncthreads();
#pragma unroll
  for (int c = 0; c < 4; c++) {
    const int p = c & 1;
    if (c + 1 < 4) stage(1 - p, c + 1);
#pragma unroll
    for (int s = 0; s < 2; s++) {
      v8bf a[4], b[4];
#pragma unroll
      for (int t = 0; t < 4; t++) {
        const int row = (wid & 1) * 64 + t * 16 + l15;
        a[t] = *(const v8bf*)&sA[p][(row << 6) + (((s * 4 + q) ^ (row & 7)) << 3)];
      }
#pragma unroll
      for (int t = 0; t < 4; t++) {
        const int row = (wid >> 1) * 64 + t * 16 + l15;
        b[t] = *(const v8bf*)&sB[p][(row << 6) + (((s * 4 + q) ^ (row & 7)) << 3)];
      }
#pragma unroll
      for (int tm = 0; tm < 4; tm++)
#pragma unroll
        for (int tn = 0; tn < 4; tn++)
          acc[tm][tn] = MFMA(a[tm], b[tn], acc[tm][tn]);
    }
    __syncthreads();
  }

#pragma unroll
  for (int tn = 0; tn < 4; tn++) {
    const int n = nblk + (wid >> 1) * 64 + tn * 16 + l15;
    const float bv = bias[n];
    const int h = n & 7;
    const int dd = n >> 3;
#pragma unroll
    for (int tm = 0; tm < 4; tm++)
#pragma unroll
      for (int r = 0; r < 4; r++) {
        const int m = mblk + (wid & 1) * 64 + tm * 16 + q * 4 + r;
        const int b = m >> 11;
        const int i = m & (L_ - 1);
        const float v = acc[tm][tn][r] + bv;
        size_t idx;
        if (MODE == 0) idx = ((size_t)(b * NH + h) * L_ + i) * DH + dd;
        else           idx = ((size_t)(b * NH + h) * DH + dd) * L_ + i;
        out[idx] = (__bf16)v;
      }
  }
}

// ---------------------------------------------------------------------------
// Score + head-softmax. Block 256 thr / 4 waves; block tile 64i x 64k, all 8
// heads in registers (acc[8][4]). Per-head LDS staging (K,Q 16KB each), dbuf.
// Grid (32, 32, nb). Writes normalized attn Pt[h][k][i] bf16.
// ---------------------------------------------------------------------------
__global__ __launch_bounds__(256, 2)
void score_softmax_kernel(const __bf16* __restrict__ Kp,
                          const __bf16* __restrict__ Qp,
                          __bf16* __restrict__ Pt, size_t ptBStride)
{
  __shared__ __bf16 sK[2][64 * 128];
  __shared__ __bf16 sQ[2][64 * 128];
  const int tid  = threadIdx.x;
  const int lane = tid & 63;
  const int wid  = tid >> 6;
  const int l15  = lane & 15;
  const int q    = lane >> 4;
  const int i0 = blockIdx.x * 64;
  const int k0 = blockIdx.y * 64;
  const int b  = blockIdx.z;

  const char* Kb = (const char*)(Kp + (size_t)b * NH * L_ * DH) + (size_t)i0 * 256;
  const char* Qb = (const char*)(Qp + (size_t)b * NH * L_ * DH) + (size_t)k0 * 256;
  __bf16* PtB = Pt + (size_t)b * ptBStride;

  auto stage = [&](int p, int h) {
    const char* Kh = Kb + (size_t)h * L_ * 256;
    const char* Qh = Qb + (size_t)h * L_ * 256;
#pragma unroll
    for (int j = 0; j < 4; j++) {
      const int slot = j * 256 + tid;
      const int row = slot >> 4, g = slot & 15;
      gl_lds16(Kh + (size_t)row * 256 + ((g ^ (row & 15)) << 4),
               &sK[p][(j * 256 + wid * 64) * 8]);
    }
#pragma unroll
    for (int j = 0; j < 4; j++) {
      const int slot = j * 256 + tid;
      const int row = slot >> 4, g = slot & 15;
      gl_lds16(Qh + (size_t)row * 256 + ((g ^ (row & 15)) << 4),
               &sQ[p][(j * 256 + wid * 64) * 8]);
    }
  };

  v4f acc[8][4];
  const v4f vz = {0.f, 0.f, 0.f, 0.f};
#pragma unroll
  for (int h = 0; h < 8; h++)
#pragma unroll
    for (int t = 0; t < 4; t++) acc[h][t] = vz;

  stage(0, 0);
  __syncthreads();
#pragma unroll
  for (int h = 0; h < 8; h++) {
    const int p = h & 1;
    if (h + 1 < 8) stage(1 - p, h + 1);
    const int arow = wid * 16 + l15;  // arow&15 == l15
#pragma unroll
    for (int s = 0; s < 4; s++) {
      const v8bf a = *(const v8bf*)&sK[p][(arow << 7) + (((s * 4 + q) ^ l15) << 3)];
#pragma unroll
      for (int t = 0; t < 4; t++) {
        const int brow = t * 16 + l15;
        const v8bf bb = *(const v8bf*)&sQ[p][(brow << 7) + (((s * 4 + q) ^ l15) << 3)];
        acc[h][t] = MFMA(a, bb, acc[h][t]);
      }
    }
    __syncthreads();
  }

  // softmax over heads (scores are tiny; no max subtraction needed)
  const float c2 = 0.12751744f;  // log2(e)/sqrt(128)
  v4f z[4];
#pragma unroll
  for (int t = 0; t < 4; t++) z[t] = vz;
#pragma unroll
  for (int h = 0; h < 8; h++)
#pragma unroll
    for (int t = 0; t < 4; t++)
#pragma unroll
      for (int r = 0; r < 4; r++) {
        const float p = exp2f(acc[h][t][r] * c2);
        acc[h][t][r] = p;
        z[t][r] += p;
      }
#pragma unroll
  for (int t = 0; t < 4; t++)
#pragma unroll
    for (int r = 0; r < 4; r++) z[t][r] = 1.0f / z[t][r];

#pragma unroll
  for (int h = 0; h < 8; h++) {
#pragma unroll
    for (int t = 0; t < 4; t++) {
      const int k = k0 + t * 16 + l15;
      const unsigned short b0 = bfbits(acc[h][t][0] * z[t][0]);
      const unsigned short b1 = bfbits(acc[h][t][1] * z[t][1]);
      const unsigned short b2 = bfbits(acc[h][t][2] * z[t][2]);
      const unsigned short b3 = bfbits(acc[h][t][3] * z[t][3]);
      uint2 w;
      w.x = (unsigned)b0 | ((unsigned)b1 << 16);
      w.y = (unsigned)b2 | ((unsigned)b3 << 16);
      *reinterpret_cast<uint2*>(PtB + (size_t)(h * L_ + k) * L_ + i0 + wid * 16 + q * 4) = w;
    }
  }
}

// ---------------------------------------------------------------------------
// PV: C[h][dd][k] = sum_i V[h][dd][i] * Pt[h][k][i]. Block 256 thr / 4 waves
// (2x2 of 64x64), block tile 128dd x 128k, chunk i=64, dbuf LDS.
// Grid (16, 8, nb). Stores hidden[(b*L+k)*HID + dd*8 + h] bf16.
// ---------------------------------------------------------------------------
__global__ __launch_bounds__(256, 2)
void pv_kernel(const __bf16* __restrict__ Vpt, const __bf16* __restrict__ Pt,
               __bf16* __restrict__ Hd, size_t ptBStride)
{
  __shared__ __bf16 sV[2][128 * 64];
  __shared__ __bf16 sP[2][128 * 64];
  const int tid  = threadIdx.x;
  const int lane = tid & 63;
  const int wid  = tid >> 6;
  const int l15  = lane & 15;
  const int q    = lane >> 4;
  const int k0 = blockIdx.x * 128;
  const int h  = blockIdx.y;
  const int b  = blockIdx.z;

  const char* Vh = (const char*)(Vpt + ((size_t)(b * NH + h) * DH) * L_);
  const char* Ph = (const char*)(Pt + (size_t)b * ptBStride + (size_t)h * L_ * L_)
                   + (size_t)k0 * 4096;
  __bf16* HdB = Hd + (size_t)b * L_ * HID;

  auto stage = [&](int p, int c) {
    const int ioff = c * 128;  // bytes
#pragma unroll
    for (int j = 0; j < 4; j++) {
      const int slot = j * 256 + tid;
      const int row = slot >> 3, g = slot & 7;
      gl_lds16(Vh + (size_t)row * 4096 + ioff + ((g ^ (row & 7)) << 4),
               &sV[p][(j * 256 + wid * 64) * 8]);
    }
#pragma unroll
    for (int j = 0; j < 4; j++) {
      const int slot = j * 256 + tid;
      const int row = slot >> 3, g = slot & 7;
      gl_lds16(Ph + (size_t)row * 4096 + ioff + ((g ^ (row & 7)) << 4),
               &sP[p][(j * 256 + wid * 64) * 8]);
    }
  };

  v4f acc[4][4];
  const v4f vz = {0.f, 0.f, 0.f, 0.f};
#pragma unroll
  for (int i = 0; i < 4; i++)
#pragma unroll
    for (int j = 0; j < 4; j++) acc[i][j] = vz;

  stage(0, 0);
  __syncthreads();
  for (int c = 0; c < 32; c++) {
    const int p = c & 1;
    if (c + 1 < 32) stage(1 - p, c + 1);
#pragma unroll
    for (int s = 0; s < 2; s++) {
      v8bf a[4], bb[4];
#pragma unroll
      for (int t = 0; t < 4; t++) {
        const int row = (wid & 1) * 64 + t * 16 + l15;
        a[t] = *(const v8bf*)&sV[p][(row << 6) + (((s * 4 + q) ^ (row & 7)) << 3)];
      }
#pragma unroll
      for (int t = 0; t < 4; t++) {
        const int row = (wid >> 1) * 64 + t * 16 + l15;
        bb[t] = *(const v8bf*)&sP[p][(row << 6) + (((s * 4 + q) ^ (row & 7)) << 3)];
      }
#pragma unroll
      for (int tm = 0; tm < 4; tm++)
#pragma unroll
        for (int tn = 0; tn < 4; tn++)
          acc[tm][tn] = MFMA(a[tm], bb[tn], acc[tm][tn]);
    }
    __syncthreads();
  }

#pragma unroll
  for (int tm = 0; tm < 4; tm++)
#pragma unroll
    for (int tn = 0; tn < 4; tn++)
#pragma unroll
      for (int r = 0; r < 4; r++) {
        const int dd = (wid & 1) * 64 + tm * 16 + q * 4 + r;
        const int k  = k0 + (wid >> 1) * 64 + tn * 16 + l15;
        HdB[(size_t)k * HID + dd * NH + h] = (__bf16)acc[tm][tn][r];
      }
}

// ---------------------------------------------------------------------------
// Output projection: out[m][n] = sum_k Hd[m][k](bf16) * Wo[n][k](fp32) + bo[n]
// Block 256 thr / 4 waves (2x2 of 32x32), tile 64x64, K=1024, chunk 64.
// B operand staged as fp32, converted after ds_read. Grid (128, 4).
// ---------------------------------------------------------------------------
__global__ __launch_bounds__(256, 2)
void outproj_kernel(const __bf16* __restrict__ Hd, const float* __restrict__ Wo,
                    const float* __restrict__ bo, float* __restrict__ out)
{
  __shared__ __bf16 sA[2][64 * 64];   // 8 KB each
  __shared__ float  sB[2][64 * 64];   // 16 KB each
  const int tid  = threadIdx.x;
  const int lane = tid & 63;
  const int wid  = tid >> 6;
  const int l15  = lane & 15;
  const int q    = lane >> 4;
  const int mblk = blockIdx.x * 64;
  const int nblk = blockIdx.y * 64;

  const char* Ab = (const char*)Hd + (size_t)mblk * 2048;
  const char* Bb = (const char*)Wo + (size_t)nblk * 4096;

  auto stage = [&](int p, int c) {
#pragma unroll
    for (int j = 0; j < 2; j++) {
      const int slot = j * 256 + tid;      // 512 slots (A: 64 rows x 8 gran)
      const int row = slot >> 3, g = slot & 7;
      gl_lds16(Ab + (size_t)row * 2048 + c * 128 + ((g ^ (row & 7)) << 4),
               &sA[p][(j * 256 + wid * 64) * 8]);
    }
#pragma unroll
    for (int j = 0; j < 4; j++) {
      const int slot = j * 256 + tid;      // 1024 slots (B: 64 rows x 16 gran)
      const int row = slot >> 4, g = slot & 15;
      gl_lds16(Bb + (size_t)row * 4096 + c * 256 + ((g ^ (row & 15)) << 4),
               &sB[p][(j * 256 + wid * 64) * 4]);
    }
  };

  v4f acc[2][2];
  const v4f vz = {0.f, 0.f, 0.f, 0.f};
#pragma unroll
  for (int i = 0; i < 2; i++)
#pragma unroll
    for (int j = 0; j < 2; j++) acc[i][j] = vz;

  stage(0, 0);
  __syncthreads();
#pragma unroll 1
  for (int c = 0; c < 16; c++) {
    const int p = c & 1;
    if (c + 1 < 16) stage(1 - p, c + 1);
#pragma unroll
    for (int s = 0; s < 2; s++) {
      v8bf a[2], bb[2];
#pragma unroll
      for (int t = 0; t < 2; t++) {
        const int row = (wid & 1) * 32 + t * 16 + l15;
        a[t] = *(const v8bf*)&sA[p][(row << 6) + (((s * 4 + q) ^ (row & 7)) << 3)];
      }
#pragma unroll
      for (int t = 0; t < 2; t++) {
        const int row = (wid >> 1) * 32 + t * 16 + l15;
        const int gg0 = s * 8 + q * 2;
        const float4 x = *(const float4*)&sB[p][(row << 6) + ((gg0 ^ l15) << 2)];
        const float4 y = *(const float4*)&sB[p][(row << 6) + (((gg0 + 1) ^ l15) << 2)];
        bb[t] = cvt8(x, y);
      }
#pragma unroll
      for (int tm = 0; tm < 2; tm++)
#pragma unroll
        for (int tn = 0; tn < 2; tn++)
          acc[tm][tn] = MFMA(a[tm], bb[tn], acc[tm][tn]);
    }
    __syncthreads();
  }

#pragma unroll
  for (int tn = 0; tn < 2; tn++) {
    const int n = nblk + (wid >> 1) * 32 + tn * 16 + l15;
    const float bv = bo[n];
#pragma unroll
    for (int tm = 0; tm < 2; tm++)
#pragma unroll
      for (int r = 0; r < 4; r++) {
        const int m = mblk + (wid & 1) * 32 + tm * 16 + q * 4 + r;
        out[(size_t)m * OUTF + n] = acc[tm][tn][r] + bv;
      }
  }
}

// ---------------------------------------------------------------------------
// Workspace (bytes):
//   0        Kp   16 MiB   [B][NH][L][DH] bf16
//   16 MiB   Qp   16 MiB
//   32 MiB   Vpt  16 MiB   [B][NH][DH][L]
//   48 MiB   Hd   16 MiB   [B][L][HID]  (first 13 MiB doubles as conv area,
//                           dead before any pv writes Hd)
//   64 MiB   Pt   64 MiB (per-batch reuse) or 256 MiB (all-batch)
// ---------------------------------------------------------------------------
extern "C" void kernel_launch(void* const* d_in, const int* in_sizes, int n_in,
                              void* d_out, int out_size, void* d_ws, size_t ws_size,
                              hipStream_t stream) {
  const float* KEY   = (const float*)d_in[0];
  const float* VALUE = (const float*)d_in[1];
  const float* QUERY = (const float*)d_in[2];
  const float* W_w   = (const float*)d_in[3];
  const float* W_b   = (const float*)d_in[4];
  const float* Wv_w  = (const float*)d_in[5];
  const float* Wv_b  = (const float*)d_in[6];
  const float* Wo_w  = (const float*)d_in[7];
  const float* Wo_b  = (const float*)d_in[8];
  float* out = (float*)d_out;

  const size_t MB = 1024 * 1024;
  char* ws = (char*)d_ws;
  __bf16* Kp  = (__bf16*)(ws);
  __bf16* Qp  = (__bf16*)(ws + 16 * MB);
  __bf16* Vpt = (__bf16*)(ws + 32 * MB);
  __bf16* Hd  = (__bf16*)(ws + 48 * MB);
  __bf16* Pt  = (__bf16*)(ws + 64 * MB);
  // conversion area inside Hd region (dead before pv writes Hd)
  __bf16* Xk  = (__bf16*)(ws + 48 * MB);
  __bf16* Xq  = (__bf16*)(ws + 48 * MB + 4 * MB);
  __bf16* Xv  = (__bf16*)(ws + 48 * MB + 8 * MB);
  __bf16* Wb  = (__bf16*)(ws + 48 * MB + 12 * MB);
  __bf16* Wvb = (__bf16*)(ws + 48 * MB + 12 * MB + 512 * 1024);

  const bool allb = ws_size >= 320 * MB;

  ConvArgs ca;
  ca.src[0] = KEY;  ca.dst[0] = Xk;  ca.n[0] = B_ * L_ * INK;
  ca.src[1] = QUERY; ca.dst[1] = Xq; ca.n[1] = B_ * L_ * INK;
  ca.src[2] = VALUE; ca.dst[2] = Xv; ca.n[2] = B_ * L_ * INK;
  ca.src[3] = W_w;  ca.dst[3] = Wb;  ca.n[3] = HID * INK;
  ca.src[4] = Wv_w; ca.dst[4] = Wvb; ca.n[4] = HID * INK;
  convert_kernel<<<dim3(2048, 5), 256, 0, stream>>>(ca);

  proj_kernel<0><<<dim3(64, 8), 256, 0, stream>>>(Xk, Wb,  W_b,  Kp);
  proj_kernel<0><<<dim3(64, 8), 256, 0, stream>>>(Xq, Wb,  W_b,  Qp);
  proj_kernel<1><<<dim3(64, 8), 256, 0, stream>>>(Xv, Wvb, Wv_b, Vpt);

  const size_t ptStride = (size_t)NH * L_ * L_;  // 33.5M elems
  if (allb) {
    score_softmax_kernel<<<dim3(32, 32, B_), 256, 0, stream>>>(Kp, Qp, Pt, ptStride);
    pv_kernel<<<dim3(16, NH, B_), 256, 0, stream>>>(Vpt, Pt, Hd, ptStride);
  } else {
    const size_t perb = (size_t)NH * L_ * DH;
    for (int b = 0; b < B_; b++) {
      score_softmax_kernel<<<dim3(32, 32, 1), 256, 0, stream>>>(
          Kp + b * perb, Qp + b * perb, Pt, 0);
      pv_kernel<<<dim3(16, NH, 1), 256, 0, stream>>>(
          Vpt + b * perb, Pt, Hd + (size_t)b * L_ * HID, 0);
    }
  }

  outproj_kernel<<<dim3(128, 4), 256, 0, stream>>>(Hd, Wo_w, Wo_b, out);
}

// Round 3
// 348.535 us; speedup vs baseline: 2.3987x; 1.2745x over previous
//
#include <hip/hip_runtime.h>
#include <hip/hip_bf16.h>
#include <stdint.h>

// Problem constants
#define B_    4
#define L_    2048
#define INK   256
#define HID   1024
#define NH    8
#define DH    128
#define OUTF  256

typedef __bf16 v8bf __attribute__((ext_vector_type(8)));
typedef float  v4f  __attribute__((ext_vector_type(4)));

#define MFMA(a,b,c) __builtin_amdgcn_mfma_f32_16x16x32_bf16((a),(b),(c),0,0,0)

__device__ __forceinline__ void gl_lds16(const void* gsrc, void* ldsbase) {
  __builtin_amdgcn_global_load_lds(
      (const __attribute__((address_space(1))) unsigned int*)(uintptr_t)gsrc,
      (__attribute__((address_space(3))) unsigned int*)(uint32_t)(uintptr_t)ldsbase,
      16, 0, 0);
}
__device__ __forceinline__ void wait_vm0()  { asm volatile("s_waitcnt vmcnt(0)" ::: "memory"); }
__device__ __forceinline__ void wait_vm8()  { asm volatile("s_waitcnt vmcnt(8)" ::: "memory"); }
__device__ __forceinline__ void wait_lgkm0(){ asm volatile("s_waitcnt lgkmcnt(0)" ::: "memory"); }
__device__ __forceinline__ void barrier_lgkm() {
  asm volatile("s_waitcnt lgkmcnt(0)\n\ts_barrier" ::: "memory");
}

__device__ __forceinline__ unsigned short bfbits(float f) {
  __bf16 h = (__bf16)f;
  return __builtin_bit_cast(unsigned short, h);
}
__device__ __forceinline__ unsigned pack2(float a, float b) {
  return (unsigned)bfbits(a) | ((unsigned)bfbits(b) << 16);
}

// ---------------------------------------------------------------------------
// fp32 -> bf16 bulk convert (KEY, QUERY, VALUE, W_w, Wv_w)
// ---------------------------------------------------------------------------
struct ConvArgs {
  const float* src[5];
  __bf16* dst[5];
  int n[5];
};
__global__ __launch_bounds__(256)
void convert_kernel(ConvArgs a) {
  const int r = blockIdx.y;
  const int i = (blockIdx.x * 256 + threadIdx.x) * 4;
  if (i >= a.n[r]) return;
  const float4 v = *(const float4*)(a.src[r] + i);
  uint2 w;
  w.x = pack2(v.x, v.y);
  w.y = pack2(v.z, v.w);
  *reinterpret_cast<uint2*>(a.dst[r] + i) = w;
}

// Wo[o][dd*8+h] fp32  ->  Wop[o][h*128+dd] bf16   (head-major permute)
__global__ __launch_bounds__(256)
void wo_perm_kernel(const float* __restrict__ Wo, __bf16* __restrict__ Wop) {
  const int o = blockIdx.x;
  const int hidp = threadIdx.x * 4;
  const int h = hidp >> 7, dd = hidp & 127;
  const float* src = Wo + (size_t)o * HID;
  const float v0 = src[(dd + 0) * 8 + h];
  const float v1 = src[(dd + 1) * 8 + h];
  const float v2 = src[(dd + 2) * 8 + h];
  const float v3 = src[(dd + 3) * 8 + h];
  uint2 w;
  w.x = pack2(v0, v1);
  w.y = pack2(v2, v3);
  *reinterpret_cast<uint2*>(Wop + (size_t)o * HID + hidp) = w;
}

// ---------------------------------------------------------------------------
// Projection (bf16 NT GEMM, K=256) — unchanged from round 2 (works well).
// MODE 0: out[((b*8+h)*L+i)*128+dd]   MODE 1: out[((b*8+h)*128+dd)*L+i]
// ---------------------------------------------------------------------------
template<int MODE>
__global__ __launch_bounds__(256, 2)
void proj_kernel(const __bf16* __restrict__ X, const __bf16* __restrict__ W,
                 const float* __restrict__ bias, __bf16* __restrict__ out)
{
  __shared__ __bf16 sA[2][128 * 64];
  __shared__ __bf16 sB[2][128 * 64];
  const int tid  = threadIdx.x;
  const int lane = tid & 63;
  const int wid  = tid >> 6;
  const int l15  = lane & 15;
  const int q    = lane >> 4;
  const int mblk = blockIdx.x * 128;
  const int nblk = blockIdx.y * 128;

  v4f acc[4][4];
  const v4f vz = {0.f, 0.f, 0.f, 0.f};
#pragma unroll
  for (int i = 0; i < 4; i++)
#pragma unroll
    for (int j = 0; j < 4; j++) acc[i][j] = vz;

  const char* Ab = (const char*)X + (size_t)mblk * 512;
  const char* Bb = (const char*)W + (size_t)nblk * 512;

  auto stage = [&](int p, int c) {
    const int koff = c * 128;
#pragma unroll
    for (int j = 0; j < 4; j++) {
      const int slot = j * 256 + tid;
      const int row = slot >> 3, g = slot & 7;
      gl_lds16(Ab + (size_t)row * 512 + koff + ((g ^ (row & 7)) << 4),
               &sA[p][(j * 256 + wid * 64) * 8]);
    }
#pragma unroll
    for (int j = 0; j < 4; j++) {
      const int slot = j * 256 + tid;
      const int row = slot >> 3, g = slot & 7;
      gl_lds16(Bb + (size_t)row * 512 + koff + ((g ^ (row & 7)) << 4),
               &sB[p][(j * 256 + wid * 64) * 8]);
    }
  };

  stage(0, 0);
  __syncthreads();
#pragma unroll
  for (int c = 0; c < 4; c++) {
    const int p = c & 1;
    if (c + 1 < 4) stage(1 - p, c + 1);
#pragma unroll
    for (int s = 0; s < 2; s++) {
      v8bf a[4], b[4];
#pragma unroll
      for (int t = 0; t < 4; t++) {
        const int row = (wid & 1) * 64 + t * 16 + l15;
        a[t] = *(const v8bf*)&sA[p][(row << 6) + (((s * 4 + q) ^ (row & 7)) << 3)];
      }
#pragma unroll
      for (int t = 0; t < 4; t++) {
        const int row = (wid >> 1) * 64 + t * 16 + l15;
        b[t] = *(const v8bf*)&sB[p][(row << 6) + (((s * 4 + q) ^ (row & 7)) << 3)];
      }
#pragma unroll
      for (int tm = 0; tm < 4; tm++)
#pragma unroll
        for (int tn = 0; tn < 4; tn++)
          acc[tm][tn] = MFMA(a[tm], b[tn], acc[tm][tn]);
    }
    __syncthreads();
  }

#pragma unroll
  for (int tn = 0; tn < 4; tn++) {
    const int n = nblk + (wid >> 1) * 64 + tn * 16 + l15;
    const float bv = bias[n];
    const int h = n & 7;
    const int dd = n >> 3;
#pragma unroll
    for (int tm = 0; tm < 4; tm++)
#pragma unroll
      for (int r = 0; r < 4; r++) {
        const int m = mblk + (wid & 1) * 64 + tm * 16 + q * 4 + r;
        const int b = m >> 11;
        const int i = m & (L_ - 1);
        const float v = acc[tm][tn][r] + bv;
        size_t idx;
        if (MODE == 0) idx = ((size_t)(b * NH + h) * L_ + i) * DH + dd;
        else           idx = ((size_t)(b * NH + h) * DH + dd) * L_ + i;
        out[idx] = (__bf16)v;
      }
  }
}

// ---------------------------------------------------------------------------
// FUSED attention: score (QK^T) + head-softmax + PV, P never leaves LDS.
// Block = 512 thr = 8 waves; wave h owns head h. Block tile: 32 k-columns,
// loops all 64 i-tiles of 32. Grid (64 ktiles, 4 batches) = 256 blocks.
// Dynamic LDS 144 KB: sK [8][32][128] | sV [8][128][32] | sP [8][32][32].
// K/V staged per-wave (global_load_lds, no cross-wave sharing -> no barrier);
// 2 lgkm-only barriers per i-tile for the cross-head softmax exchange.
// Output: Hd[b*L + k][h*128 + dd] bf16 (head-major hidden).
// ---------------------------------------------------------------------------
__global__ __launch_bounds__(512, 2)
void fused_attn_kernel(const __bf16* __restrict__ Kp,
                       const __bf16* __restrict__ Qp,
                       const __bf16* __restrict__ Vpt,
                       __bf16* __restrict__ Hd)
{
  extern __shared__ char smem[];
  char* sK = smem;                    // 64 KB: per head 8 KB, rows 256 B (16 gran)
  char* sV = smem + 65536;            // 64 KB: per head 8 KB, rows  64 B (4 gran)
  char* sP = smem + 131072;           // 16 KB: [h][k 32][i 32] bf16

  const int tid  = threadIdx.x;
  const int lane = tid & 63;
  const int h    = tid >> 6;          // wave id == head
  const int l15  = lane & 15;
  const int q    = lane >> 4;
  const int k0   = blockIdx.x * 32;
  const int b    = blockIdx.y;

  const char* KpH = (const char*)Kp  + (size_t)(b * NH + h) * L_ * DH * 2;
  const char* QpH = (const char*)Qp  + (size_t)(b * NH + h) * L_ * DH * 2;
  const char* VpH = (const char*)Vpt + (size_t)(b * NH + h) * DH * L_ * 2;
  char* sKh = sK + h * 8192;
  char* sVh = sV + h * 8192;
  char* sPh = sP + h * 2048;

  auto stage_K = [&](int i0) {
#pragma unroll
    for (int j = 0; j < 8; j++) {
      const int slot = j * 64 + lane;
      const int row = slot >> 4, g = slot & 15;
      gl_lds16(KpH + (size_t)(i0 + row) * 256 + ((g ^ (row & 15)) << 4),
               sKh + j * 1024);
    }
  };
  auto stage_V = [&](int i0) {
#pragma unroll
    for (int j = 0; j < 8; j++) {
      const int slot = j * 64 + lane;
      const int row = slot >> 2, g = slot & 3;
      gl_lds16(VpH + (size_t)row * 4096 + (size_t)i0 * 2 + ((g ^ (row & 3)) << 4),
               sVh + j * 1024);
    }
  };

  stage_K(0);
  stage_V(0);

  // Q fragments, held in registers for the whole kernel: [ksub 2][dchunk 4]
  v8bf qf[2][4];
#pragma unroll
  for (int n = 0; n < 2; n++)
#pragma unroll
    for (int c = 0; c < 4; c++)
      qf[n][c] = *(const v8bf*)(QpH + (size_t)(k0 + n * 16 + l15) * 256 + c * 64 + q * 16);

  v4f cacc[8][2];
  const v4f vz = {0.f, 0.f, 0.f, 0.f};
#pragma unroll
  for (int t = 0; t < 8; t++)
#pragma unroll
    for (int n = 0; n < 2; n++) cacc[t][n] = vz;

  const float c2 = 0.12751744f;  // log2(e)/sqrt(128)
  const int ip = tid & 15;        // normalize-phase mapping: i-pair
  const int kk = tid >> 4;        // and k (0..31)

  for (int it = 0; it < 64; ++it) {
    const int i0 = it * 32;
    // K(it), V(it) resident once <=8 loads outstanding (the newer 8 may be V(it)
    // only at it==0 where Q's 8 reg-loads are newest; V still drained there? no:
    // it==0 outstanding = K8,V8,Q8 -> vmcnt(8) drains K+V. it>0: K8,V8 -> drains K.)
    wait_vm8();

    // ---- score phase: read all K A-frags, then allow overwrite ----
    v8bf ka[2][4];
#pragma unroll
    for (int si = 0; si < 2; si++)
#pragma unroll
      for (int c = 0; c < 4; c++) {
        const int row = si * 16 + l15;
        ka[si][c] = *(const v8bf*)(sKh + row * 256 + (((c * 4 + q) ^ l15) << 4));
      }
    wait_lgkm0();
    if (it + 1 < 64) stage_K(i0 + 32);

    v4f s[2][2];
#pragma unroll
    for (int si = 0; si < 2; si++)
#pragma unroll
      for (int n = 0; n < 2; n++) s[si][n] = vz;
#pragma unroll
    for (int c = 0; c < 4; c++)
#pragma unroll
      for (int si = 0; si < 2; si++)
#pragma unroll
        for (int n = 0; n < 2; n++)
          s[si][n] = MFMA(ka[si][c], qf[n][c], s[si][n]);

    // exp + write P~ to sP[h][k][i] (4 consecutive i per lane)
#pragma unroll
    for (int si = 0; si < 2; si++)
#pragma unroll
      for (int n = 0; n < 2; n++) {
        const float p0 = exp2f(s[si][n][0] * c2);
        const float p1 = exp2f(s[si][n][1] * c2);
        const float p2 = exp2f(s[si][n][2] * c2);
        const float p3 = exp2f(s[si][n][3] * c2);
        uint2 w;
        w.x = pack2(p0, p1);
        w.y = pack2(p2, p3);
        *(uint2*)(sPh + (n * 16 + l15) * 64 + (si * 16 + q * 4) * 2) = w;
      }
    barrier_lgkm();

    // ---- normalize across heads: thread owns (k=kk, i = 2*ip, 2*ip+1) ----
    {
      unsigned u[8];
      float lo[8], hi[8], s0 = 0.f, s1 = 0.f;
#pragma unroll
      for (int hh = 0; hh < 8; hh++)
        u[hh] = *(const unsigned*)(sP + hh * 2048 + kk * 64 + ip * 4);
#pragma unroll
      for (int hh = 0; hh < 8; hh++) {
        lo[hh] = __builtin_bit_cast(float, u[hh] << 16);
        hi[hh] = __builtin_bit_cast(float, u[hh] & 0xFFFF0000u);
        s0 += lo[hh];
        s1 += hi[hh];
      }
      const float r0 = __builtin_amdgcn_rcpf(s0);
      const float r1 = __builtin_amdgcn_rcpf(s1);
#pragma unroll
      for (int hh = 0; hh < 8; hh++)
        *(unsigned*)(sP + hh * 2048 + kk * 64 + ip * 4) = pack2(lo[hh] * r0, hi[hh] * r1);
    }
    barrier_lgkm();

    // ---- PV phase: read V A-frags + P B-frags, allow overwrite, MFMA ----
    v8bf va[8], pb[2];
#pragma unroll
    for (int t = 0; t < 8; t++) {
      const int row = t * 16 + l15;
      va[t] = *(const v8bf*)(sVh + row * 64 + ((q ^ (row & 3)) << 4));
    }
#pragma unroll
    for (int n = 0; n < 2; n++)
      pb[n] = *(const v8bf*)(sPh + (n * 16 + l15) * 64 + q * 16);
    wait_lgkm0();
    if (it + 1 < 64) stage_V(i0 + 32);
    else wait_vm0();  // nothing left to prefetch; keep counts sane
#pragma unroll
    for (int t = 0; t < 8; t++)
#pragma unroll
      for (int n = 0; n < 2; n++)
        cacc[t][n] = MFMA(va[t], pb[n], cacc[t][n]);
  }

  // ---- epilogue: C[dd=128][k=32] -> Hd[b*L + k][h*128 + dd] ----
#pragma unroll
  for (int t = 0; t < 8; t++)
#pragma unroll
    for (int n = 0; n < 2; n++) {
      uint2 w;
      w.x = pack2(cacc[t][n][0], cacc[t][n][1]);
      w.y = pack2(cacc[t][n][2], cacc[t][n][3]);
      char* dst = (char*)Hd +
          (((size_t)(b * L_ + k0 + n * 16 + l15)) * HID + h * DH + t * 16 + q * 4) * 2;
      *(uint2*)dst = w;
    }
}

// ---------------------------------------------------------------------------
// Output projection (pure bf16): out[m][o] = sum Hd[m][k]*Wop[o][k] + bo[o]
// Tile 64x64, 4 waves (2x2 of 32x32), K=1024 in 16 chunks, dbuf. Grid (128,4).
// ---------------------------------------------------------------------------
__global__ __launch_bounds__(256, 2)
void outproj_kernel(const __bf16* __restrict__ Hd, const __bf16* __restrict__ Wop,
                    const float* __restrict__ bo, float* __restrict__ out)
{
  __shared__ __bf16 sA[2][64 * 64];
  __shared__ __bf16 sB[2][64 * 64];
  const int tid  = threadIdx.x;
  const int lane = tid & 63;
  const int wid  = tid >> 6;
  const int l15  = lane & 15;
  const int q    = lane >> 4;
  const int mblk = blockIdx.x * 64;
  const int nblk = blockIdx.y * 64;

  const char* Ab = (const char*)Hd  + (size_t)mblk * 2048;
  const char* Bb = (const char*)Wop + (size_t)nblk * 2048;

  auto stage = [&](int p, int c) {
#pragma unroll
    for (int j = 0; j < 2; j++) {
      const int slot = j * 256 + tid;
      const int row = slot >> 3, g = slot & 7;
      gl_lds16(Ab + (size_t)row * 2048 + c * 128 + ((g ^ (row & 7)) << 4),
               &sA[p][(j * 256 + wid * 64) * 8]);
    }
#pragma unroll
    for (int j = 0; j < 2; j++) {
      const int slot = j * 256 + tid;
      const int row = slot >> 3, g = slot & 7;
      gl_lds16(Bb + (size_t)row * 2048 + c * 128 + ((g ^ (row & 7)) << 4),
               &sB[p][(j * 256 + wid * 64) * 8]);
    }
  };

  v4f acc[2][2];
  const v4f vz = {0.f, 0.f, 0.f, 0.f};
#pragma unroll
  for (int i = 0; i < 2; i++)
#pragma unroll
    for (int j = 0; j < 2; j++) acc[i][j] = vz;

  stage(0, 0);
  __syncthreads();
#pragma unroll 1
  for (int c = 0; c < 16; c++) {
    const int p = c & 1;
    if (c + 1 < 16) stage(1 - p, c + 1);
#pragma unroll
    for (int s = 0; s < 2; s++) {
      v8bf a[2], bb[2];
#pragma unroll
      for (int t = 0; t < 2; t++) {
        const int row = (wid & 1) * 32 + t * 16 + l15;
        a[t] = *(const v8bf*)&sA[p][(row << 6) + (((s * 4 + q) ^ (row & 7)) << 3)];
      }
#pragma unroll
      for (int t = 0; t < 2; t++) {
        const int row = (wid >> 1) * 32 + t * 16 + l15;
        bb[t] = *(const v8bf*)&sB[p][(row << 6) + (((s * 4 + q) ^ (row & 7)) << 3)];
      }
#pragma unroll
      for (int tm = 0; tm < 2; tm++)
#pragma unroll
        for (int tn = 0; tn < 2; tn++)
          acc[tm][tn] = MFMA(a[tm], bb[tn], acc[tm][tn]);
    }
    __syncthreads();
  }

#pragma unroll
  for (int tn = 0; tn < 2; tn++) {
    const int n = nblk + (wid >> 1) * 32 + tn * 16 + l15;
    const float bv = bo[n];
#pragma unroll
    for (int tm = 0; tm < 2; tm++)
#pragma unroll
      for (int r = 0; r < 4; r++) {
        const int m = mblk + (wid & 1) * 32 + tm * 16 + q * 4 + r;
        out[(size_t)m * OUTF + n] = acc[tm][tn][r] + bv;
      }
  }
}

// ---------------------------------------------------------------------------
// Workspace layout (bytes):
//   0      Kp   16 MiB  [B*NH][L][DH] bf16
//   16 MiB Qp   16 MiB
//   32 MiB Vpt  16 MiB  [B*NH][DH][L]
//   48 MiB Hd   16 MiB  [B*L][h*128+dd]  (conv X/W area inside, dead by then)
//   64 MiB Wop  512 KiB [O][h*128+dd] bf16
// ---------------------------------------------------------------------------
extern "C" void kernel_launch(void* const* d_in, const int* in_sizes, int n_in,
                              void* d_out, int out_size, void* d_ws, size_t ws_size,
                              hipStream_t stream) {
  const float* KEY   = (const float*)d_in[0];
  const float* VALUE = (const float*)d_in[1];
  const float* QUERY = (const float*)d_in[2];
  const float* W_w   = (const float*)d_in[3];
  const float* W_b   = (const float*)d_in[4];
  const float* Wv_w  = (const float*)d_in[5];
  const float* Wv_b  = (const float*)d_in[6];
  const float* Wo_w  = (const float*)d_in[7];
  const float* Wo_b  = (const float*)d_in[8];
  float* out = (float*)d_out;

  const size_t MB = 1024 * 1024;
  char* ws = (char*)d_ws;
  __bf16* Kp  = (__bf16*)(ws);
  __bf16* Qp  = (__bf16*)(ws + 16 * MB);
  __bf16* Vpt = (__bf16*)(ws + 32 * MB);
  __bf16* Hd  = (__bf16*)(ws + 48 * MB);
  __bf16* Wop = (__bf16*)(ws + 64 * MB);
  // conversion area inside Hd region (dead before fused_attn writes Hd)
  __bf16* Xk  = (__bf16*)(ws + 48 * MB);
  __bf16* Xq  = (__bf16*)(ws + 48 * MB + 4 * MB);
  __bf16* Xv  = (__bf16*)(ws + 48 * MB + 8 * MB);
  __bf16* Wb  = (__bf16*)(ws + 48 * MB + 12 * MB);
  __bf16* Wvb = (__bf16*)(ws + 48 * MB + 12 * MB + 512 * 1024);

  ConvArgs ca;
  ca.src[0] = KEY;   ca.dst[0] = Xk;  ca.n[0] = B_ * L_ * INK;
  ca.src[1] = QUERY; ca.dst[1] = Xq;  ca.n[1] = B_ * L_ * INK;
  ca.src[2] = VALUE; ca.dst[2] = Xv;  ca.n[2] = B_ * L_ * INK;
  ca.src[3] = W_w;   ca.dst[3] = Wb;  ca.n[3] = HID * INK;
  ca.src[4] = Wv_w;  ca.dst[4] = Wvb; ca.n[4] = HID * INK;
  convert_kernel<<<dim3(2048, 5), 256, 0, stream>>>(ca);
  wo_perm_kernel<<<dim3(256), 256, 0, stream>>>(Wo_w, Wop);

  proj_kernel<0><<<dim3(64, 8), 256, 0, stream>>>(Xk, Wb,  W_b,  Kp);
  proj_kernel<0><<<dim3(64, 8), 256, 0, stream>>>(Xq, Wb,  W_b,  Qp);
  proj_kernel<1><<<dim3(64, 8), 256, 0, stream>>>(Xv, Wvb, Wv_b, Vpt);

  fused_attn_kernel<<<dim3(64, B_), 512, 147456, stream>>>(Kp, Qp, Vpt, Hd);

  outproj_kernel<<<dim3(128, 4), 256, 0, stream>>>(Hd, Wop, Wo_b, out);
}